// Round 11
// baseline (100.744 us; speedup 1.0000x reference)
//
#include <hip/hip_runtime.h>
#include <math.h>

// Match numpy (no FMA fusion) for all decision-critical arithmetic.
#pragma clang fp contract(off)

#define IMG_H 240
#define IMG_W 320
#define NPX   (IMG_H * IMG_W)
#define NCH   11
#define NSLICE 8       // face-dim parallelism: grid.z slices
#define CULL_M 1e-3f   // conservative SAT-cull margin (e-units; |err| <~ 1e-5)
#define EZ_M   1e-5f   // early-z margin (>> 4e-7 fp bound on depth vs min(pz))

struct ProjM { float m[16]; };   // row-major numpy proj (after row-1 flip)

// Shared transform helper — EXACT reference DAG (contract off).
__device__ __forceinline__ void xform(float x, float y, float z,
                                      const float* __restrict__ pose,
                                      const ProjM& P,
                                      float& px, float& py, float& pz,
                                      float& iw, float& wc) {
  float c0 = ((x*pose[0]     + y*pose[1])     + z*pose[2])     + pose[3];
  float c1 = ((x*(-pose[4])  + y*(-pose[5]))  + z*(-pose[6]))  + (-pose[7]);
  float c2 = ((x*(-pose[8])  + y*(-pose[9]))  + z*(-pose[10])) + (-pose[11]);
  float c3 = ((x*pose[12]    + y*pose[13])    + z*pose[14])    + pose[15];
  float q0 = ((c0*P.m[0]  + c1*P.m[1])  + c2*P.m[2])  + c3*P.m[3];
  float q1 = ((c0*P.m[4]  + c1*P.m[5])  + c2*P.m[6])  + c3*P.m[7];
  float q2 = ((c0*P.m[8]  + c1*P.m[9])  + c2*P.m[10]) + c3*P.m[11];
  float q3 = ((c0*P.m[12] + c1*P.m[13]) + c2*P.m[14]) + c3*P.m[15];
  wc = q3;
  float denw = (fabsf(wc) > 1e-9f) ? wc : 1e-9f;
  iw = 1.0f / denw;
  float ndx = q0 * iw, ndy = q1 * iw;
  pz = q2 * iw;
  px = ((ndx + 1.0f) * 0.5f) * (float)IMG_W;
  py = ((1.0f - ndy) * 0.5f) * (float)IMG_H;
}

// decode high-32 of a packed zkey back to its depth float
__device__ __forceinline__ float keydepth(unsigned long long k) {
  unsigned u = (unsigned)(k >> 32);
  u = (u & 0x80000000u) ? (u ^ 0x80000000u) : ~u;
  return __uint_as_float(u);
}

// Fused per-face kernel + zkey init (grid covers NPX/256 blocks; face work
// on the first F indices). Corner transforms recomputed per face —
// bit-identical to a per-vertex pass (same DAG, contraction off).
// Reference's e0/e1/e2 are NOT standard barycentrics:
//   e0 = -lambda_A, e1 = -lambda_B, e2 = 2 - lambda_C; accepted region
//   {e>=0} is the triangle point-reflected through vertex C. Culling uses
//   (a) that region's bbox and (b) fp64-derived affine edge coefficients.
// fe[2f+0].w carries the face's zmin (for depth-prune in cull).
extern "C" __global__ void k_face(const float* __restrict__ verts,
                                  const int* __restrict__ faces,
                                  const float* __restrict__ pose,
                                  ProjM P,
                                  float* __restrict__ vnacc,
                                  float4* __restrict__ frec,
                                  float4* __restrict__ fbb,
                                  float4* __restrict__ fe,
                                  int4*  __restrict__ fidx,
                                  unsigned long long* __restrict__ zkey,
                                  int F) {
  int i = blockIdx.x * 256 + threadIdx.x;
  if (i < NPX) zkey[i] = ~0ull;
  int f = i;
  if (f >= F) return;
  int i0 = faces[3*f+0], i1 = faces[3*f+1], i2 = faces[3*f+2];
  float x0 = verts[3*i0+0], y0 = verts[3*i0+1], z0 = verts[3*i0+2];
  float x1 = verts[3*i1+0], y1 = verts[3*i1+1], z1 = verts[3*i1+2];
  float x2 = verts[3*i2+0], y2 = verts[3*i2+1], z2 = verts[3*i2+2];

  // ---- face normal accumulation (unchanged DAG) ----
  {
    float ux = x1 - x0, uy = y1 - y0, uz = z1 - z0;
    float vx = x2 - x0, vy = y2 - y0, vz = z2 - z0;
    float fx = uy*vz - uz*vy;
    float fy = uz*vx - ux*vz;
    float fz = ux*vy - uy*vx;
    float n = sqrtf((fx*fx + fy*fy) + fz*fz);
    float d = fmaxf(n, 1e-12f);
    fx = fx / d; fy = fy / d; fz = fz / d;
    atomicAdd(&vnacc[3*i0+0], fx); atomicAdd(&vnacc[3*i0+1], fy); atomicAdd(&vnacc[3*i0+2], fz);
    atomicAdd(&vnacc[3*i1+0], fx); atomicAdd(&vnacc[3*i1+1], fy); atomicAdd(&vnacc[3*i1+2], fz);
    atomicAdd(&vnacc[3*i2+0], fx); atomicAdd(&vnacc[3*i2+1], fy); atomicAdd(&vnacc[3*i2+2], fz);
  }

  float ax, ay, pz0, iw0, w0;  xform(x0, y0, z0, pose, P, ax, ay, pz0, iw0, w0);
  float bx, by, pz1, iw1, w1;  xform(x1, y1, z1, pose, P, bx, by, pz1, iw1, w1);
  float cx, cy, pz2, iw2, w2;  xform(x2, y2, z2, pose, P, cx, cy, pz2, iw2, w2);

  float area = (bx - ax) * (cy - ay) - (by - ay) * (cx - ax);
  float inva = 1.0f / ((fabsf(area) > 1e-12f) ? area : 1e-12f);
  bool valid = (w0 > 1e-6f) && (w1 > 1e-6f) && (w2 > 1e-6f) && (fabsf(area) > 1e-12f);
  float rax = 2.0f*cx - ax, ray = 2.0f*cy - ay;
  float rbx = 2.0f*cx - bx, rby = 2.0f*cy - by;
  float minx = fminf(cx, fminf(rax, rbx)), maxx = fmaxf(cx, fmaxf(rax, rbx));
  float miny = fminf(cy, fminf(ray, rby)), maxy = fmaxf(cy, fmaxf(ray, rby));
  frec[4*f+0] = make_float4(bx, by, cy - by, cx - bx);
  frec[4*f+1] = make_float4(cx, cy, ay - cy, ax - cx);
  frec[4*f+2] = make_float4(inva, pz0, pz1, pz2);
  frec[4*f+3] = make_float4(iw0, iw1, iw2, 0.0f);
  fbb[f] = valid ? make_float4(minx, maxx, miny, maxy)
                 : make_float4(1e30f, -1e30f, 1e30f, -1e30f);
  fidx[f] = make_int4(i0, i1, i2, 0);
  float zmn = fminf(pz0, fminf(pz1, pz2));
  {
    double dbx = bx, dby = by, dcx = cx, dcy = cy, dax = ax, day = ay;
    double dinv = (double)inva;
    double d0 = dcy - dby, d1 = dcx - dbx;
    double d2 = day - dcy, d3 = dax - dcx;
    double a0 = d0 * dinv, b0 = -d1 * dinv, c0 = (dby * d1 - dbx * d0) * dinv;
    double a1 = d2 * dinv, b1 = -d3 * dinv, c1 = (dcy * d3 - dcx * d2) * dinv;
    fe[2*f+0] = make_float4((float)a0, (float)b0, (float)c0, zmn);
    fe[2*f+1] = make_float4((float)a1, (float)b1, (float)c1, 0.0f);
  }
}

// Pass A: 16x16 px per 256-thread block (4 waves x 8x8 subtiles), face-slice
// on grid.z. Per chunk: (1) re-read this pixel's zkey (volatile — other
// slices' atomicMin results arrive mid-kernel; merging a foreign candidate
// into bestkey is safe: the final atomicMin of it is a no-op, and as a
// pruning bound it only removes faces whose keys are provably greater);
// (2) wmax = wave-max(bestd); (3) lane-j cull = bbox + SAT + zmin-prune
// (fe[2f].w, margin EZ_M >> 4e-7 depth-vs-zmin fp bound — strict-key
// argument keeps ties exact); (4) survivors evaluated with the verbatim
// reference DAG, winner tracked as packed u64 (depth,orig_idx) — exactly
// the reference's chunk-argmin + strict-< carry semantics.
extern "C" __global__ __launch_bounds__(256)
void k_rasterA(const float4* __restrict__ frec,
               const float4* __restrict__ fbb,
               const float4* __restrict__ fe,
               unsigned long long* zkey,
               int F, int nslice) {
  int t = threadIdx.x;
  int wave = t >> 6;                  // 0..3
  int lane = t & 63;
  int sx = (wave & 1) * 8, sy = (wave >> 1) * 8;
  int pxi = blockIdx.x * 16 + sx + (lane & 7);
  int pyi = blockIdx.y * 16 + sy + (lane >> 3);
  float X = (float)pxi + 0.5f;
  float Y = (float)pyi + 0.5f;
  float tXlo = (float)(blockIdx.x * 16 + sx) + 0.5f, tXhi = tXlo + 7.0f;
  float tYlo = (float)(blockIdx.y * 16 + sy) + 0.5f, tYhi = tYlo + 7.0f;
  size_t pix = (size_t)pyi * IMG_W + pxi;
  volatile unsigned long long* vz = zkey;

  int f0 = blockIdx.z * nslice;
  int f1 = min(F, f0 + nslice);

  unsigned long long bestkey = ~0ull;
  float bestd = 1e9f;

  for (int base = f0; base < f1; base += 64) {
    // cross-slice z-share: merge current global candidate for this pixel
    unsigned long long kz = vz[pix];
    if (kz < bestkey) { bestkey = kz; bestd = keydepth(kz); }
    float mx = bestd;
    #pragma unroll
    for (int off = 1; off < 64; off <<= 1) mx = fmaxf(mx, __shfl_xor(mx, off));
    float wmax = mx;

    int f = base + lane;
    bool ov = false;
    if (f < f1) {
      float4 bb = fbb[f];
      ov = (bb.x - 1.0f <= tXhi) && (bb.y + 1.0f >= tXlo) &&
           (bb.z - 1.0f <= tYhi) && (bb.w + 1.0f >= tYlo);
      if (ov) {
        float4 E0 = fe[2*f+0];
        float4 E1 = fe[2*f+1];
        float pa0 = E0.x * tXlo, pb0 = E0.x * tXhi;
        float qa0 = E0.y * tYlo, qb0 = E0.y * tYhi;
        float e0mx = (fmaxf(pa0, pb0) + fmaxf(qa0, qb0)) + E0.z;
        float e0mn = (fminf(pa0, pb0) + fminf(qa0, qb0)) + E0.z;
        float pa1 = E1.x * tXlo, pb1 = E1.x * tXhi;
        float qa1 = E1.y * tYlo, qb1 = E1.y * tYhi;
        float e1mx = (fmaxf(pa1, pb1) + fmaxf(qa1, qb1)) + E1.z;
        float e1mn = (fminf(pa1, pb1) + fminf(qa1, qb1)) + E1.z;
        float e2mx = (1.0f - e0mn) - e1mn;   // upper bound of e2 = 1-e0-e1
        ov = (e0mx >= -CULL_M) && (e1mx >= -CULL_M) && (e2mx >= -CULL_M) &&
             (E0.w - EZ_M < wmax);           // depth-prune vs shared bound
      }
    }
    unsigned long long mask = __ballot(ov);

    while (mask) {
      int j = __builtin_ctzll(mask);
      mask &= mask - 1;
      int ju = __builtin_amdgcn_readfirstlane(base + j);   // wave-uniform
      const float4* fr = frec + (size_t)ju * 4;
      float4 C = fr[2];   // inva, pz0, pz1, pz2
      float zminf = fminf(C.y, fminf(C.z, C.w));
      if (!(wmax > zminf - EZ_M)) continue;   // conservative (wmax stale-high)
      float4 A = fr[0];   // bx, by, d0, d1
      float4 B = fr[1];   // cx, cy, d2, d3
      float t0 = (X - A.x) * A.z;
      float t1 = (Y - A.y) * A.w;
      float e0 = (t0 - t1) * C.x;
      float t2 = (X - B.x) * B.z;
      float t3 = (Y - B.y) * B.w;
      float e1 = (t2 - t3) * C.x;
      float e2 = (1.0f - e0) - e1;
      float depth = ((e0 * C.y) + (e1 * C.z)) + (e2 * C.w);
      bool inside = (e0 >= 0.0f) && (e1 >= 0.0f) && (e2 >= 0.0f) &&
                    (depth >= -1.0f) && (depth <= 1.0f);
      if (inside) {
        unsigned int ub = __float_as_uint(depth);
        ub = (ub & 0x80000000u) ? ~ub : (ub | 0x80000000u);   // order-preserving
        unsigned long long key = ((unsigned long long)ub << 32) | (unsigned)ju;
        if (key < bestkey) { bestkey = key; bestd = depth; }
      }
    }
  }

  if (bestkey != ~0ull) atomicMin(&zkey[pix], bestkey);
}

// Pass B: per-pixel resolve with fused per-vertex work — recompute winner's
// barycentrics (same DAG as rasterA), then the winner's three vertices'
// normals and world positions directly from verts/vnacc (identical DAGs to
// the reference vertex path). Interpolate, stage in LDS, coalesced stores.
extern "C" __global__ __launch_bounds__(256)
void k_resolve(const unsigned long long* __restrict__ zkey,
               const float4* __restrict__ frec,
               const int4* __restrict__ fidx,
               const float* __restrict__ verts,
               const float* __restrict__ vnacc,
               const float* __restrict__ pose,
               float* __restrict__ out) {
  __shared__ float sOut[256 * NCH];   // 11 KB
  int t = threadIdx.x;
  int p = blockIdx.x * 256 + t;       // NPX = 300 * 256 exactly
  int pyi = p / IMG_W, pxi = p - pyi * IMG_W;
  float X = (float)pxi + 0.5f;
  float Y = (float)pyi + 0.5f;
  unsigned long long key = zkey[p];

  float oc[NCH];
  if (key != ~0ull) {
    int besti = (int)(key & 0xFFFFFFFFu);
    const float4* fr = frec + (size_t)besti * 4;
    float4 A = fr[0], B = fr[1], C = fr[2], D = fr[3];
    float t0 = (X - A.x) * A.z;
    float t1 = (Y - A.y) * A.w;
    float e0 = (t0 - t1) * C.x;
    float t2 = (X - B.x) * B.z;
    float t3 = (Y - B.y) * B.w;
    float e1 = (t2 - t3) * C.x;
    float b2 = (1.0f - e0) - e1;
    float p0 = e0 * D.x, p1 = e1 * D.y, p2 = b2 * D.z;
    float den = (p0 + p1) + p2;
    if (!(fabsf(den) > 1e-12f)) den = 1e-12f;
    float u0 = p0 / den, u1 = p1 / den, u2 = p2 / den;
    int4 vi = fidx[besti];

    float cv[3][NCH];
    int vidx[3] = { vi.x, vi.y, vi.z };
    #pragma unroll
    for (int k = 0; k < 3; ++k) {
      int i = vidx[k];
      float x = verts[3*i+0], y = verts[3*i+1], z = verts[3*i+2];
      float nx = vnacc[3*i+0], ny = vnacc[3*i+1], nz = vnacc[3*i+2];
      float nn = sqrtf((nx*nx + ny*ny) + nz*nz);
      float nm = fmaxf(nn, 1e-12f);
      nx = nx / nm; ny = ny / nm; nz = nz / nm;
      float v3x = ((x*pose[0] + y*pose[1]) + z*pose[2])  + pose[3];
      float v3y = ((x*pose[4] + y*pose[5]) + z*pose[6])  + pose[7];
      float v3z = ((x*pose[8] + y*pose[9]) + z*pose[10]) + pose[11];
      cv[k][0] = 1.0f;
      cv[k][1] = v3x; cv[k][2] = v3y; cv[k][3] = v3z;
      cv[k][4] = nx;  cv[k][5] = ny;  cv[k][6] = nz;
      cv[k][7] = x;   cv[k][8] = y;   cv[k][9] = z;
      cv[k][10] = 1.0f;
    }
    #pragma unroll
    for (int ch = 0; ch < NCH; ++ch)
      oc[ch] = (u0 * cv[0][ch] + u1 * cv[1][ch]) + u2 * cv[2][ch];
  } else {
    #pragma unroll
    for (int ch = 0; ch < NCH; ++ch) oc[ch] = 0.0f;
  }
  #pragma unroll
  for (int ch = 0; ch < NCH; ++ch) sOut[t * NCH + ch] = oc[ch];
  __syncthreads();
  float4* o4 = (float4*)(out + (size_t)blockIdx.x * 256 * NCH);
  const float4* s4 = (const float4*)sOut;
  #pragma unroll
  for (int k = 0; k < 3; ++k) {
    int idx = t + k * 256;
    if (idx < 704) o4[idx] = s4[idx];
  }
}

extern "C" void kernel_launch(void* const* d_in, const int* in_sizes, int n_in,
                              void* d_out, int out_size, void* d_ws, size_t ws_size,
                              hipStream_t stream) {
  const float* verts = (const float*)d_in[0];
  const int*   faces = (const int*)d_in[1];
  const float* pose  = (const float*)d_in[2];
  float* out = (float*)d_out;
  int V = in_sizes[0] / 3;
  int F = in_sizes[1] / 3;

  // workspace layout (float units, 16B-aligned chunks)
  float* ws = (float*)d_ws;
  size_t o = 0;
  auto alloc = [&](size_t n) { size_t r = o; o += (n + 3) & ~(size_t)3; return r; };
  size_t o_zk   = alloc((size_t)2 * NPX);     // u64 zkey buffer
  size_t o_vn   = alloc((size_t)3 * V);
  size_t o_fr   = alloc((size_t)16 * F);
  size_t o_bb   = alloc((size_t)4 * F);
  size_t o_fe   = alloc((size_t)8 * F);
  size_t o_fi   = alloc((size_t)4 * F);
  unsigned long long* zkey = (unsigned long long*)(ws + o_zk);
  float*  vnacc = ws + o_vn;
  float4* frec  = (float4*)(ws + o_fr);
  float4* fbb   = (float4*)(ws + o_bb);
  float4* fe    = (float4*)(ws + o_fe);
  int4*   fidx  = (int4*)(ws + o_fi);

  // projection matrix: double math then f32 cast, matching numpy
  double fxd = 286.2057, sd = 0.0, cxd = 162.6306;
  double fyd = 286.7852, cyd = 121.0245;
  double wd = IMG_W, hd = IMG_H, ncd = 0.1, fcd = 10.0;
  double q  = -(fcd + ncd) / (fcd - ncd);
  double qn = -2.0 * fcd * ncd / (fcd - ncd);
  double Pd[16] = {
    2.0*fxd/wd, -2.0*sd/wd, (-2.0*cxd + wd)/wd, 0.0,
    0.0,        2.0*fyd/hd, (2.0*cyd - hd)/hd, -0.0,
    0.0,        0.0,        q,                  qn,
    0.0,        0.0,       -1.0,                0.0 };
  ProjM P;
  for (int i = 0; i < 16; ++i) P.m[i] = (float)Pd[i];

  hipMemsetAsync(vnacc, 0, (size_t)3 * V * sizeof(float), stream);
  k_face<<<(NPX + 255) / 256, 256, 0, stream>>>(verts, faces, pose, P, vnacc,
                                                frec, fbb, fe, fidx, zkey, F);
  int nslice = (F + NSLICE - 1) / NSLICE;
  dim3 g(IMG_W / 16, IMG_H / 16, NSLICE);
  k_rasterA<<<g, 256, 0, stream>>>(frec, fbb, fe, zkey, F, nslice);
  k_resolve<<<NPX / 256, 256, 0, stream>>>(zkey, frec, fidx, verts, vnacc, pose, out);
}

// Round 12
// 89.948 us; speedup vs baseline: 1.1200x; 1.1200x over previous
//
#include <hip/hip_runtime.h>
#include <math.h>

// Match numpy (no FMA fusion) for all decision-critical arithmetic.
#pragma clang fp contract(off)

#define IMG_H 240
#define IMG_W 320
#define NPX   (IMG_H * IMG_W)
#define NCH   11
#define NCHP  12       // padded color stride (3 x float4)
#define NSLICE 8       // face-dim parallelism: grid.z slices
#define CULL_M 1e-3f   // conservative SAT-cull margin (e-units; |err| <~ 1e-5)
#define EZ_M   1e-5f   // early-z margin (>> 4e-7 fp bound on depth vs min(pz))

struct ProjM { float m[16]; };   // row-major numpy proj (after row-1 flip)

// One init dispatch: zero vnacc, set zkey buffer to "empty" (all 1s).
extern "C" __global__ void k_init(float* __restrict__ vnacc, int n3v,
                                  unsigned long long* __restrict__ zkey) {
  int i = blockIdx.x * 256 + threadIdx.x;
  if (i < n3v) vnacc[i] = 0.0f;
  if (i < NPX) zkey[i] = ~0ull;
}

// Shared transform helper — EXACT reference DAG (contract off).
__device__ __forceinline__ void xform(float x, float y, float z,
                                      const float* __restrict__ pose,
                                      const ProjM& P,
                                      float& px, float& py, float& pz,
                                      float& iw, float& wc) {
  float c0 = ((x*pose[0]     + y*pose[1])     + z*pose[2])     + pose[3];
  float c1 = ((x*(-pose[4])  + y*(-pose[5]))  + z*(-pose[6]))  + (-pose[7]);
  float c2 = ((x*(-pose[8])  + y*(-pose[9]))  + z*(-pose[10])) + (-pose[11]);
  float c3 = ((x*pose[12]    + y*pose[13])    + z*pose[14])    + pose[15];
  float q0 = ((c0*P.m[0]  + c1*P.m[1])  + c2*P.m[2])  + c3*P.m[3];
  float q1 = ((c0*P.m[4]  + c1*P.m[5])  + c2*P.m[6])  + c3*P.m[7];
  float q2 = ((c0*P.m[8]  + c1*P.m[9])  + c2*P.m[10]) + c3*P.m[11];
  float q3 = ((c0*P.m[12] + c1*P.m[13]) + c2*P.m[14]) + c3*P.m[15];
  wc = q3;
  float denw = (fabsf(wc) > 1e-9f) ? wc : 1e-9f;
  iw = 1.0f / denw;
  float ndx = q0 * iw, ndy = q1 * iw;
  pz = q2 * iw;
  px = ((ndx + 1.0f) * 0.5f) * (float)IMG_W;
  py = ((1.0f - ndy) * 0.5f) * (float)IMG_H;
}

// Fused per-face kernel: face-normal atomics + face setup (recomputes its 3
// corner transforms directly — bit-identical to a per-vertex pass since the
// expression DAG is identical and contraction is off).
//
// Reference's e0/e1/e2 are NOT standard barycentrics:
//   e0 = -lambda_A, e1 = -lambda_B, e2 = 2 - lambda_C; accepted region
//   {e>=0} is the triangle point-reflected through vertex C. Culling uses
//   (a) that region's bbox and (b) fp64-derived affine edge coefficients.
// frec layout (16 floats, 64 B) — eval side, reference DAG operands:
//   [0..3]  bx, by, d0=(cy-by), d1=(cx-bx)
//   [4..7]  cx, cy, d2=(ay-cy), d3=(ax-cx)
//   [8..11] inva, pz0, pz1, pz2
//   [12..15] iw0, iw1, iw2, 0
extern "C" __global__ void k_face(const float* __restrict__ verts,
                                  const int* __restrict__ faces,
                                  const float* __restrict__ pose,
                                  ProjM P,
                                  float* __restrict__ vnacc,
                                  float4* __restrict__ frec,
                                  float4* __restrict__ fbb,
                                  float4* __restrict__ fe,
                                  int4*  __restrict__ fidx, int F) {
  int f = blockIdx.x * 64 + threadIdx.x;
  if (f >= F) return;
  int i0 = faces[3*f+0], i1 = faces[3*f+1], i2 = faces[3*f+2];
  float x0 = verts[3*i0+0], y0 = verts[3*i0+1], z0 = verts[3*i0+2];
  float x1 = verts[3*i1+0], y1 = verts[3*i1+1], z1 = verts[3*i1+2];
  float x2 = verts[3*i2+0], y2 = verts[3*i2+1], z2 = verts[3*i2+2];

  // ---- face normal accumulation (unchanged DAG) ----
  {
    float ux = x1 - x0, uy = y1 - y0, uz = z1 - z0;
    float vx = x2 - x0, vy = y2 - y0, vz = z2 - z0;
    float fx = uy*vz - uz*vy;
    float fy = uz*vx - ux*vz;
    float fz = ux*vy - uy*vx;
    float n = sqrtf((fx*fx + fy*fy) + fz*fz);
    float d = fmaxf(n, 1e-12f);
    fx = fx / d; fy = fy / d; fz = fz / d;
    atomicAdd(&vnacc[3*i0+0], fx); atomicAdd(&vnacc[3*i0+1], fy); atomicAdd(&vnacc[3*i0+2], fz);
    atomicAdd(&vnacc[3*i1+0], fx); atomicAdd(&vnacc[3*i1+1], fy); atomicAdd(&vnacc[3*i1+2], fz);
    atomicAdd(&vnacc[3*i2+0], fx); atomicAdd(&vnacc[3*i2+1], fy); atomicAdd(&vnacc[3*i2+2], fz);
  }

  // ---- corner transforms (identical DAG to reference vertex path) ----
  float ax, ay, pz0, iw0, w0;  xform(x0, y0, z0, pose, P, ax, ay, pz0, iw0, w0);
  float bx, by, pz1, iw1, w1;  xform(x1, y1, z1, pose, P, bx, by, pz1, iw1, w1);
  float cx, cy, pz2, iw2, w2;  xform(x2, y2, z2, pose, P, cx, cy, pz2, iw2, w2);

  float area = (bx - ax) * (cy - ay) - (by - ay) * (cx - ax);
  float inva = 1.0f / ((fabsf(area) > 1e-12f) ? area : 1e-12f);
  bool valid = (w0 > 1e-6f) && (w1 > 1e-6f) && (w2 > 1e-6f) && (fabsf(area) > 1e-12f);
  // reflected-triangle vertices {C, 2C-A, 2C-B}
  float rax = 2.0f*cx - ax, ray = 2.0f*cy - ay;
  float rbx = 2.0f*cx - bx, rby = 2.0f*cy - by;
  float minx = fminf(cx, fminf(rax, rbx)), maxx = fmaxf(cx, fmaxf(rax, rbx));
  float miny = fminf(cy, fminf(ray, rby)), maxy = fmaxf(cy, fmaxf(ray, rby));
  frec[4*f+0] = make_float4(bx, by, cy - by, cx - bx);
  frec[4*f+1] = make_float4(cx, cy, ay - cy, ax - cx);
  frec[4*f+2] = make_float4(inva, pz0, pz1, pz2);
  frec[4*f+3] = make_float4(iw0, iw1, iw2, 0.0f);
  fbb[f] = valid ? make_float4(minx, maxx, miny, maxy)
                 : make_float4(1e30f, -1e30f, 1e30f, -1e30f);
  fidx[f] = make_int4(i0, i1, i2, 0);
  // affine edge coefficients, fp64 for tight error:
  //   e0 = ((X-bx)*d0 - (Y-by)*d1)*inva = a0*X + b0*Y + c0
  {
    double dbx = bx, dby = by, dcx = cx, dcy = cy, dax = ax, day = ay;
    double dinv = (double)inva;
    double d0 = dcy - dby, d1 = dcx - dbx;
    double d2 = day - dcy, d3 = dax - dcx;
    double a0 = d0 * dinv, b0 = -d1 * dinv, c0 = (dby * d1 - dbx * d0) * dinv;
    double a1 = d2 * dinv, b1 = -d3 * dinv, c1 = (dcy * d3 - dcx * d2) * dinv;
    fe[2*f+0] = make_float4((float)a0, (float)b0, (float)c0, 0.0f);
    fe[2*f+1] = make_float4((float)a1, (float)b1, (float)c1, 0.0f);
  }
}

// Per-vertex: normalize accumulated normal, world-space position, colors.
// Colors padded to stride 12 -> three float4 stores/loads.
extern "C" __global__ void k_vertex(const float* __restrict__ verts,
                                    const float* __restrict__ vnacc,
                                    const float* __restrict__ pose,
                                    float4* __restrict__ colors, int V) {
  int i = blockIdx.x * 64 + threadIdx.x;
  if (i >= V) return;
  float x = verts[3*i+0], y = verts[3*i+1], z = verts[3*i+2];

  float nx = vnacc[3*i+0], ny = vnacc[3*i+1], nz = vnacc[3*i+2];
  float nn = sqrtf((nx*nx + ny*ny) + nz*nz);
  float nm = fmaxf(nn, 1e-12f);
  nx = nx / nm; ny = ny / nm; nz = nz / nm;

  float v3x = ((x*pose[0] + y*pose[1]) + z*pose[2])  + pose[3];
  float v3y = ((x*pose[4] + y*pose[5]) + z*pose[6])  + pose[7];
  float v3z = ((x*pose[8] + y*pose[9]) + z*pose[10]) + pose[11];

  colors[3*i+0] = make_float4(1.0f, v3x, v3y, v3z);   // ch 0..3
  colors[3*i+1] = make_float4(nx, ny, nz, x);         // ch 4..7
  colors[3*i+2] = make_float4(y, z, 1.0f, 0.0f);      // ch 8..10, pad
}

// Pass A: 16x16 pixel region per 256-thread block (4 waves x 8x8 subtiles),
// face-slice on grid.z. No LDS, no barriers. Per 64-face chunk, lane j
// culls face j: reflected-bbox test + SAT via affine edge extrema at tile
// corners. Ballot -> survivors are wave-uniform, records read on the
// scalar path. Early-z: depth is a convex combination of (pz0,pz1,pz2),
// so a face whose min(pz) >= every lane's bestd (margin EZ_M) can't win
// -> skip after reading only frec[2]. Winner = lexicographic min of
// (depth, face_idx) via packed u64 atomicMin — exactly the reference's
// chunk-argmin + strict-< carry semantics.
extern "C" __global__ __launch_bounds__(256)
void k_rasterA(const float4* __restrict__ frec,
               const float4* __restrict__ fbb,
               const float4* __restrict__ fe,
               unsigned long long* __restrict__ zkey,
               int F, int nslice) {
  int t = threadIdx.x;
  int wave = t >> 6;                  // 0..3
  int lane = t & 63;
  int sx = (wave & 1) * 8, sy = (wave >> 1) * 8;
  int pxi = blockIdx.x * 16 + sx + (lane & 7);
  int pyi = blockIdx.y * 16 + sy + (lane >> 3);
  float X = (float)pxi + 0.5f;
  float Y = (float)pyi + 0.5f;
  float tXlo = (float)(blockIdx.x * 16 + sx) + 0.5f, tXhi = tXlo + 7.0f;
  float tYlo = (float)(blockIdx.y * 16 + sy) + 0.5f, tYhi = tYlo + 7.0f;

  int f0 = blockIdx.z * nslice;
  int f1 = min(F, f0 + nslice);

  float bestd = 1e9f;
  int   besti = -1;

  for (int base = f0; base < f1; base += 64) {
    int f = base + lane;
    bool ov = false;
    if (f < f1) {
      float4 bb = fbb[f];
      ov = (bb.x - 1.0f <= tXhi) && (bb.y + 1.0f >= tXlo) &&
           (bb.z - 1.0f <= tYhi) && (bb.w + 1.0f >= tYlo);
      if (ov) {
        float4 E0 = fe[2*f+0];
        float4 E1 = fe[2*f+1];
        float pa0 = E0.x * tXlo, pb0 = E0.x * tXhi;
        float qa0 = E0.y * tYlo, qb0 = E0.y * tYhi;
        float e0mx = (fmaxf(pa0, pb0) + fmaxf(qa0, qb0)) + E0.z;
        float e0mn = (fminf(pa0, pb0) + fminf(qa0, qb0)) + E0.z;
        float pa1 = E1.x * tXlo, pb1 = E1.x * tXhi;
        float qa1 = E1.y * tYlo, qb1 = E1.y * tYhi;
        float e1mx = (fmaxf(pa1, pb1) + fmaxf(qa1, qb1)) + E1.z;
        float e1mn = (fminf(pa1, pb1) + fminf(qa1, qb1)) + E1.z;
        float e2mx = (1.0f - e0mn) - e1mn;   // upper bound of e2 = 1-e0-e1
        ov = (e0mx >= -CULL_M) && (e1mx >= -CULL_M) && (e2mx >= -CULL_M);
      }
    }
    unsigned long long mask = __ballot(ov);

    while (mask) {
      int j = __builtin_ctzll(mask);
      mask &= mask - 1;
      int ju = __builtin_amdgcn_readfirstlane(base + j);   // wave-uniform
      const float4* fr = frec + (size_t)ju * 4;
      float4 C = fr[2];   // inva, pz0, pz1, pz2
      // early-z: no lane can beat a face whose min depth >= its bestd
      float zminf = fminf(C.y, fminf(C.z, C.w));
      if (__ballot(bestd > zminf - EZ_M) == 0ull) continue;
      float4 A = fr[0];   // bx, by, d0, d1
      float4 B = fr[1];   // cx, cy, d2, d3
      float t0 = (X - A.x) * A.z;
      float t1 = (Y - A.y) * A.w;
      float e0 = (t0 - t1) * C.x;
      float t2 = (X - B.x) * B.z;
      float t3 = (Y - B.y) * B.w;
      float e1 = (t2 - t3) * C.x;
      float e2 = (1.0f - e0) - e1;
      float depth = ((e0 * C.y) + (e1 * C.z)) + (e2 * C.w);
      bool inside = (e0 >= 0.0f) && (e1 >= 0.0f) && (e2 >= 0.0f) &&
                    (depth >= -1.0f) && (depth <= 1.0f);
      if (inside && depth < bestd) {
        bestd = depth; besti = base + j;
      }
    }
  }

  if (besti >= 0) {
    unsigned int ub = __float_as_uint(bestd);
    ub = (ub & 0x80000000u) ? ~ub : (ub | 0x80000000u);   // order-preserving
    unsigned long long key = ((unsigned long long)ub << 32) | (unsigned int)besti;
    atomicMin(&zkey[(size_t)pyi * IMG_W + pxi], key);
  }
}

// Pass B: per-pixel resolve — recompute winner's barycentrics (same DAG as
// rasterA), interpolate with vectorized color loads, stage in LDS, write
// fully-coalesced float4s.
extern "C" __global__ __launch_bounds__(256)
void k_resolve(const unsigned long long* __restrict__ zkey,
               const float4* __restrict__ frec,
               const float4* __restrict__ colors,
               const int4* __restrict__ fidx,
               float* __restrict__ out) {
  __shared__ float sOut[256 * NCH];   // 11 KB
  int t = threadIdx.x;
  int p = blockIdx.x * 256 + t;       // NPX = 300 * 256 exactly
  int pyi = p / IMG_W, pxi = p - pyi * IMG_W;
  float X = (float)pxi + 0.5f;
  float Y = (float)pyi + 0.5f;
  unsigned long long key = zkey[p];

  float oc[NCH];
  if (key != ~0ull) {
    int besti = (int)(key & 0xFFFFFFFFu);
    const float4* fr = frec + (size_t)besti * 4;
    float4 A = fr[0], B = fr[1], C = fr[2], D = fr[3];
    float t0 = (X - A.x) * A.z;
    float t1 = (Y - A.y) * A.w;
    float e0 = (t0 - t1) * C.x;
    float t2 = (X - B.x) * B.z;
    float t3 = (Y - B.y) * B.w;
    float e1 = (t2 - t3) * C.x;
    float b2 = (1.0f - e0) - e1;
    float p0 = e0 * D.x, p1 = e1 * D.y, p2 = b2 * D.z;
    float den = (p0 + p1) + p2;
    if (!(fabsf(den) > 1e-12f)) den = 1e-12f;
    float u0 = p0 / den, u1 = p1 / den, u2 = p2 / den;
    int4 vi = fidx[besti];
    float c0v[NCHP], c1v[NCHP], c2v[NCHP];
    #pragma unroll
    for (int k = 0; k < 3; ++k) {
      *(float4*)(c0v + 4*k) = colors[3*vi.x + k];
      *(float4*)(c1v + 4*k) = colors[3*vi.y + k];
      *(float4*)(c2v + 4*k) = colors[3*vi.z + k];
    }
    #pragma unroll
    for (int ch = 0; ch < NCH; ++ch)
      oc[ch] = (u0 * c0v[ch] + u1 * c1v[ch]) + u2 * c2v[ch];
  } else {
    #pragma unroll
    for (int ch = 0; ch < NCH; ++ch) oc[ch] = 0.0f;
  }
  #pragma unroll
  for (int ch = 0; ch < NCH; ++ch) sOut[t * NCH + ch] = oc[ch];
  __syncthreads();
  // 256*11 = 2816 floats = 704 float4s, contiguous; block offset 16B-aligned
  float4* o4 = (float4*)(out + (size_t)blockIdx.x * 256 * NCH);
  const float4* s4 = (const float4*)sOut;
  #pragma unroll
  for (int k = 0; k < 3; ++k) {
    int idx = t + k * 256;
    if (idx < 704) o4[idx] = s4[idx];
  }
}

extern "C" void kernel_launch(void* const* d_in, const int* in_sizes, int n_in,
                              void* d_out, int out_size, void* d_ws, size_t ws_size,
                              hipStream_t stream) {
  const float* verts = (const float*)d_in[0];
  const int*   faces = (const int*)d_in[1];
  const float* pose  = (const float*)d_in[2];
  float* out = (float*)d_out;
  int V = in_sizes[0] / 3;
  int F = in_sizes[1] / 3;

  // workspace layout (float units, 16B-aligned chunks)
  float* ws = (float*)d_ws;
  size_t o = 0;
  auto alloc = [&](size_t n) { size_t r = o; o += (n + 3) & ~(size_t)3; return r; };
  size_t o_zk   = alloc((size_t)2 * NPX);     // u64 zkey buffer
  size_t o_vn   = alloc((size_t)3 * V);
  size_t o_col  = alloc((size_t)NCHP * V);
  size_t o_fr   = alloc((size_t)16 * F);
  size_t o_bb   = alloc((size_t)4 * F);
  size_t o_fe   = alloc((size_t)8 * F);
  size_t o_fi   = alloc((size_t)4 * F);
  unsigned long long* zkey = (unsigned long long*)(ws + o_zk);
  float*  vnacc = ws + o_vn;
  float4* col   = (float4*)(ws + o_col);
  float4* frec  = (float4*)(ws + o_fr);
  float4* fbb   = (float4*)(ws + o_bb);
  float4* fe    = (float4*)(ws + o_fe);
  int4*   fidx  = (int4*)(ws + o_fi);

  // projection matrix: double math then f32 cast, matching numpy
  double fxd = 286.2057, sd = 0.0, cxd = 162.6306;
  double fyd = 286.7852, cyd = 121.0245;
  double wd = IMG_W, hd = IMG_H, ncd = 0.1, fcd = 10.0;
  double q  = -(fcd + ncd) / (fcd - ncd);
  double qn = -2.0 * fcd * ncd / (fcd - ncd);
  double Pd[16] = {
    2.0*fxd/wd, -2.0*sd/wd, (-2.0*cxd + wd)/wd, 0.0,
    0.0,        2.0*fyd/hd, (2.0*cyd - hd)/hd, -0.0,
    0.0,        0.0,        q,                  qn,
    0.0,        0.0,       -1.0,                0.0 };
  ProjM P;
  for (int i = 0; i < 16; ++i) P.m[i] = (float)Pd[i];

  int n3v = 3 * V;
  int initN = (NPX > n3v) ? NPX : n3v;
  k_init<<<(initN + 255) / 256, 256, 0, stream>>>(vnacc, n3v, zkey);
  k_face<<<(F + 63) / 64, 64, 0, stream>>>(verts, faces, pose, P, vnacc,
                                           frec, fbb, fe, fidx, F);
  k_vertex<<<(V + 63) / 64, 64, 0, stream>>>(verts, vnacc, pose, col, V);
  int nslice = (F + NSLICE - 1) / NSLICE;
  dim3 g(IMG_W / 16, IMG_H / 16, NSLICE);
  k_rasterA<<<g, 256, 0, stream>>>(frec, fbb, fe, zkey, F, nslice);
  k_resolve<<<NPX / 256, 256, 0, stream>>>(zkey, frec, col, fidx, out);
}